// Round 14
// baseline (119.564 us; speedup 1.0000x reference)
//
#include <hip/hip_runtime.h>
#include <cstdint>

// B=4, S=512, D=512, H=8, TM=20, DH=64
// out layout: out[1048576] | attn[8388608] | reg[1] | T_i[2048]  (all float)

typedef __attribute__((ext_vector_type(8))) _Float16 f16x8;
typedef __attribute__((ext_vector_type(4))) float f32x4;

__device__ __forceinline__ float sep_mad(float a, float b, float c) {
    // separate mul+add rounding (matches numpy), blocks FMA contraction:
    // spike threshold is discontinuous.
    float t = a * b;
    asm volatile("" : "+v"(t));
    return t + c;
}

union HU4 { _Float16 h[4]; ushort4 u; };
union HU8 { _Float16 h[8]; uint4 u; };
union HU2 { _Float16 h[2]; unsigned u; };

__device__ __forceinline__ void split4(float4 v, HU4& hi, HU4& lo) {
    hi.h[0] = (_Float16)v.x; lo.h[0] = (_Float16)(v.x - (float)hi.h[0]);
    hi.h[1] = (_Float16)v.y; lo.h[1] = (_Float16)(v.y - (float)hi.h[1]);
    hi.h[2] = (_Float16)v.z; lo.h[2] = (_Float16)(v.z - (float)hi.h[2]);
    hi.h[3] = (_Float16)v.w; lo.h[3] = (_Float16)(v.w - (float)hi.h[3]);
}

__device__ __forceinline__ void cast4(float4 v, HU4& hi) {
    hi.h[0] = (_Float16)v.x; hi.h[1] = (_Float16)v.y;
    hi.h[2] = (_Float16)v.z; hi.h[3] = (_Float16)v.w;
}

// ---------------- Kernel 1: mixed-precision MFMA GEMM + fused LIF/bitpack epilogue ----------
// QKV N-blocks (bn<1536, fp16): tile = 64 tokens x 64 dims of one (proj,head) ->
//   epilogue stages acc to LDS, runs 20-step LIF per element, ballot-packs q/k spikes
//   (UNMASKED -- t<T mask deferred to k_scores_av) and a 20-bit v-history word.
// Gate N-blocks (bn>=1536, fp16x3 hi/lo): write raw h1 to h1buf (T_i needs exactness).
__global__ __launch_bounds__(256) void k_gemm3(
    const float* __restrict__ X,
    const float* __restrict__ Wq, const float* __restrict__ Wk,
    const float* __restrict__ Wv, const float* __restrict__ gw1,
    const float* __restrict__ cw1,
    const float* __restrict__ pAlpha, const float* __restrict__ pBeta,
    unsigned long long* __restrict__ qbits,  // [(bh*20)+t]*512 + s   (raw)
    unsigned long long* __restrict__ kbits,  // same layout           (raw)
    unsigned* __restrict__ vbits,            // [tok][512 vdims] 20-bit history
    float* __restrict__ h1buf)               // [2048][128] raw h1 (gate cols)
{
    __shared__ _Float16 AsH[4][64][8];
    __shared__ _Float16 BsH[4][64][8];
    __shared__ float LT[64][64];             // 16 KB: gate blocks alias AsL/BsL here
    _Float16 (*AsL)[64][8] = reinterpret_cast<_Float16 (*)[64][8]>(&LT[0][0]);
    _Float16 (*BsL)[64][8] = reinterpret_cast<_Float16 (*)[64][8]>(((char*)&LT[0][0]) + 4096);

    const int bn = blockIdx.x * 64, bm = blockIdx.y * 64;
    const int tid = threadIdx.x, w = tid >> 6, l = tid & 63;
    const int mB = (w & 1) * 32, nB = (w >> 1) * 32;
    const int sr = tid >> 2, sk = tid & 3;
    const int fr = l & 15, fk = l >> 4;
    const bool gate = (bn >= 1536);           // block-uniform

    const float* asrc = X + (bm + sr) * 512;
    const int brow = bn + sr;
    const float* bsrc;
    bool bvalid = true;
    if      (brow < 512)  bsrc = Wq  + brow * 512;
    else if (brow < 1024) bsrc = Wk  + (brow - 512) * 512;
    else if (brow < 1536) bsrc = Wv  + (brow - 1024) * 512;
    else if (brow < 1600) bsrc = gw1 + (brow - 1536) * 512;
    else if (brow < 1632) bsrc = cw1 + (brow - 1600) * 512;
    else { bsrc = Wq; bvalid = false; }

    f32x4 acc[2][2] = {};
    const float4 z4{0.f, 0.f, 0.f, 0.f};

    float4 pa0 = *(const float4*)(asrc + sk * 8);
    float4 pa1 = *(const float4*)(asrc + sk * 8 + 4);
    float4 pb0 = bvalid ? *(const float4*)(bsrc + sk * 8)     : z4;
    float4 pb1 = bvalid ? *(const float4*)(bsrc + sk * 8 + 4) : z4;

    for (int k0 = 0; k0 < 512; k0 += 32) {
        __syncthreads();
        if (gate) {
            HU4 h0, l0, h1, l1;
            split4(pa0, h0, l0); split4(pa1, h1, l1);
            *(ushort4*)&AsH[sk][sr][0] = h0.u; *(ushort4*)&AsH[sk][sr][4] = h1.u;
            *(ushort4*)&AsL[sk][sr][0] = l0.u; *(ushort4*)&AsL[sk][sr][4] = l1.u;
            split4(pb0, h0, l0); split4(pb1, h1, l1);
            *(ushort4*)&BsH[sk][sr][0] = h0.u; *(ushort4*)&BsH[sk][sr][4] = h1.u;
            *(ushort4*)&BsL[sk][sr][0] = l0.u; *(ushort4*)&BsL[sk][sr][4] = l1.u;
        } else {
            HU4 h0, h1;
            cast4(pa0, h0); cast4(pa1, h1);
            *(ushort4*)&AsH[sk][sr][0] = h0.u; *(ushort4*)&AsH[sk][sr][4] = h1.u;
            cast4(pb0, h0); cast4(pb1, h1);
            *(ushort4*)&BsH[sk][sr][0] = h0.u; *(ushort4*)&BsH[sk][sr][4] = h1.u;
        }
        __syncthreads();
        const int kn = (k0 + 32) & 511;   // wraps harmlessly on last iter
        pa0 = *(const float4*)(asrc + kn + sk * 8);
        pa1 = *(const float4*)(asrc + kn + sk * 8 + 4);
        if (bvalid) {
            pb0 = *(const float4*)(bsrc + kn + sk * 8);
            pb1 = *(const float4*)(bsrc + kn + sk * 8 + 4);
        }

        f16x8 ah[2];
#pragma unroll
        for (int mt = 0; mt < 2; mt++)
            ah[mt] = *(const f16x8*)&AsH[fk][mB + mt * 16 + fr][0];
        if (gate) {
            f16x8 al[2];
#pragma unroll
            for (int mt = 0; mt < 2; mt++)
                al[mt] = *(const f16x8*)&AsL[fk][mB + mt * 16 + fr][0];
#pragma unroll
            for (int nt = 0; nt < 2; nt++) {
                f16x8 bh = *(const f16x8*)&BsH[fk][nB + nt * 16 + fr][0];
                f16x8 bl = *(const f16x8*)&BsL[fk][nB + nt * 16 + fr][0];
#pragma unroll
                for (int mt = 0; mt < 2; mt++) {
                    acc[mt][nt] = __builtin_amdgcn_mfma_f32_16x16x32_f16(ah[mt], bh, acc[mt][nt], 0, 0, 0);
                    acc[mt][nt] = __builtin_amdgcn_mfma_f32_16x16x32_f16(ah[mt], bl, acc[mt][nt], 0, 0, 0);
                    acc[mt][nt] = __builtin_amdgcn_mfma_f32_16x16x32_f16(al[mt], bh, acc[mt][nt], 0, 0, 0);
                }
            }
        } else {
#pragma unroll
            for (int nt = 0; nt < 2; nt++) {
                f16x8 bh = *(const f16x8*)&BsH[fk][nB + nt * 16 + fr][0];
#pragma unroll
                for (int mt = 0; mt < 2; mt++)
                    acc[mt][nt] = __builtin_amdgcn_mfma_f32_16x16x32_f16(ah[mt], bh, acc[mt][nt], 0, 0, 0);
            }
        }
    }

    if (gate) {
        // store raw h1 columns (j-1536) to h1buf
#pragma unroll
        for (int mt = 0; mt < 2; mt++) {
#pragma unroll
            for (int nt = 0; nt < 2; nt++) {
                const int jc = (bn - 1536) + nB + nt * 16 + fr;
#pragma unroll
                for (int rr = 0; rr < 4; rr++) {
                    const int i = bm + mB + mt * 16 + fk * 4 + rr;
                    h1buf[i * 128 + jc] = acc[mt][nt][rr];
                }
            }
        }
        return;
    }

    // ---- fused LIF epilogue (QKV blocks) ----
    // stage acc -> LT[token_local][dim_local]
#pragma unroll
    for (int mt = 0; mt < 2; mt++)
#pragma unroll
        for (int nt = 0; nt < 2; nt++)
#pragma unroll
            for (int rr = 0; rr < 4; rr++)
                LT[mB + mt * 16 + fk * 4 + rr][nB + nt * 16 + fr] = acc[mt][nt][rr];
    __syncthreads();

    const int p = bn >> 9;                    // 0=q, 1=k, 2=v
    const int h = (bn & 511) >> 6;
    const float alpha = pAlpha[0], beta = pBeta[0];
    for (int tt = 0; tt < 16; tt++) {
        const int tok = w * 16 + tt;
        const int gtok = bm + tok;
        const int b = gtok >> 9, s = gtok & 511;
        const float inp = LT[tok][l];         // lane = dim
        float ii = 0.f, vv = 0.f;
        if (p < 2) {
            unsigned long long* dst = (p == 0) ? qbits : kbits;
            const long base = ((long)((b * 8 + h) * 20)) * 512 + s;
#pragma unroll
            for (int t = 0; t < 20; t++) {
                ii = sep_mad(alpha, ii, inp); vv = sep_mad(beta, vv, ii);
                bool sp = vv >= 1.0f; vv = sp ? 0.f : vv;
                unsigned long long m = __ballot(sp);
                if (l == 0) dst[base + t * 512] = m;
            }
        } else {
            unsigned vw = 0;
#pragma unroll
            for (int t = 0; t < 20; t++) {
                ii = sep_mad(alpha, ii, inp); vv = sep_mad(beta, vv, ii);
                bool sp = vv >= 1.0f; vv = sp ? 0.f : vv;
                vw |= ((unsigned)sp) << t;
            }
            vbits[(long)(b * 512 + s) * 512 + h * 64 + l] = vw;
        }
    }
}

// ---------------- Kernel 2: gate layers 2+3 -> T_i (round-8 proven structure) ----------------
__global__ __launch_bounds__(256) void k_gates2(
    const float* __restrict__ h1raw,          // [2048][128] raw
    const float* __restrict__ gb1, const float* __restrict__ cb1,
    const float* __restrict__ gw2, const float* __restrict__ gb2,
    const float* __restrict__ gw3, const float* __restrict__ gb3,
    const float* __restrict__ cw2, const float* __restrict__ cb2,
    int* __restrict__ Ti, float* __restrict__ ti_out)
{
    __shared__ float h1s[32][100];
    __shared__ float w2s[32][65];    // 65-pad: conflict-free
    __shared__ float h2s[32][36];
    const int tok0 = blockIdx.x * 32;
    const int tid = threadIdx.x;

    for (int i = tid; i < 2048; i += 256) w2s[i >> 6][i & 63] = gw2[i];
    for (int i = tid; i < 3072; i += 256) {
        const int r = i / 96, c = i % 96;
        const float v = h1raw[(long)(tok0 + r) * 128 + c] + (c < 64 ? gb1[c] : cb1[c - 64]);
        h1s[r][c] = fmaxf(v, 0.f);
    }
    __syncthreads();

#pragma unroll
    for (int it = 0; it < 4; it++) {
        const int tok = (tid >> 5) + it * 8, o2 = tid & 31;
        float a = gb2[o2];
        for (int k = 0; k < 64; k++) a = fmaf(w2s[o2][k], h1s[tok][k], a);
        h2s[tok][o2] = fmaxf(a, 0.f);
    }
    __syncthreads();

    if (tid < 32) {
        const int tok = tid;
        float gg = gb3[0], cc = cb2[0];
        for (int k = 0; k < 32; k++) {
            gg = fmaf(gw3[k], h2s[tok][k], gg);
            cc = fmaf(cw2[k], h1s[tok][64 + k], cc);
        }
        float g = 1.f / (1.f + expf(-gg));
        float c = 1.f / (1.f + expf(-cc));
        float p1 = 0.7f * g, p2 = 0.3f * c;
        asm volatile("" : "+v"(p1), "+v"(p2));
        float comb = p1 + p2;
        float tf = ceilf(comb * 20.0f);
        tf = fminf(fmaxf(tf, 1.f), 20.f);
        Ti[tok0 + tok] = (int)tf;
        ti_out[tok0 + tok] = tf;
    }
}

// ---------------- Kernel 3: masked popcount scores + softmax -> attn + fused AV ----------------
// qs masked by T_row at staging; kv masked by T_col at load (term survives iff
// t < T_i AND t < T_j -- exactly the reference zeroing). AV B-operand computed
// on the fly from vbits: (fp16)(popcount(vw & ((1<<T_s)-1)) / 20) == old vmT.
__global__ __launch_bounds__(256) void k_scores_av(
    const unsigned long long* __restrict__ qbits,
    const unsigned long long* __restrict__ kbits,
    const unsigned* __restrict__ vbits,
    float* __restrict__ attn,
    const int* __restrict__ Ti, float* __restrict__ regp,
    _Float16* __restrict__ hout)        // [tok][h*64+d] fp16
{
    const int bh = blockIdx.x >> 5;            // 0..31
    const int i0 = (blockIdx.x & 31) * 16;
    const int base = bh * 20 * 512;
    const int b = bh >> 3, h = bh & 7;
    __shared__ unsigned long long qs[20][16];
    __shared__ _Float16 sc16[16][520];         // pad 520: rows 1040B, 16B-aligned
    __shared__ unsigned tmask[512];            // (1<<T_s)-1 per token of batch b
    const int tid = threadIdx.x;

    for (int i = tid; i < 512; i += 256) {
        const int T = Ti[b * 512 + i];
        tmask[i] = (1u << T) - 1u;
    }
    __syncthreads();

    int Tmax = 0;
    const int tb = b * 512 + i0;
#pragma unroll
    for (int r = 0; r < 16; r++) Tmax = max(Tmax, Ti[tb + r]);
    for (int idx = tid; idx < 320; idx += 256) {
        int t = idx >> 4, r = idx & 15;
        unsigned long long w = qbits[base + t * 512 + i0 + r];
        qs[t][r] = ((tmask[i0 + r] >> t) & 1u) ? w : 0ull;   // row mask t < T_i
    }
    __syncthreads();

    {
        const unsigned long long* kbp = kbits + base + 2 * tid;
        const unsigned m0 = tmask[2 * tid], m1 = tmask[2 * tid + 1];
        int acc0[16] = {}, acc1[16] = {};
        for (int tc = 0; tc < 4; tc++) {
            if (tc * 5 >= Tmax) break;
            unsigned long long kv0[5], kv1[5];
#pragma unroll
            for (int t = 0; t < 5; t++) {
                ulonglong2 kk = *(const ulonglong2*)(kbp + (tc * 5 + t) * 512);
                kv0[t] = ((m0 >> (tc * 5 + t)) & 1u) ? kk.x : 0ull;   // col mask t < T_j
                kv1[t] = ((m1 >> (tc * 5 + t)) & 1u) ? kk.y : 0ull;
            }
#pragma unroll
            for (int r = 0; r < 16; r++) {
#pragma unroll
                for (int t = 0; t < 5; t++) {
                    unsigned long long qv = qs[tc * 5 + t][r];
                    acc0[r] += __popcll(qv & kv0[t]);
                    acc1[r] += __popcll(qv & kv1[t]);
                }
            }
        }
#pragma unroll
        for (int r = 0; r < 16; r++) {
            HU2 p;                              // counts <= 1280: *0.125 exact in fp16
            p.h[0] = (_Float16)((float)acc0[r] * 0.125f);
            p.h[1] = (_Float16)((float)acc1[r] * 0.125f);
            *(unsigned*)&sc16[r][2 * tid] = p.u;
        }
    }
    __syncthreads();

    const int wid = tid >> 6, lane = tid & 63;
#pragma unroll
    for (int rr = 0; rr < 4; rr++) {
        const int r = wid * 4 + rr;
        float vals[8];
        float m = -1e30f;
#pragma unroll
        for (int k = 0; k < 8; k++) { vals[k] = (float)sc16[r][lane + 64 * k]; m = fmaxf(m, vals[k]); }
#pragma unroll
        for (int off = 32; off; off >>= 1) m = fmaxf(m, __shfl_xor(m, off));
        float sum = 0.f;
#pragma unroll
        for (int k = 0; k < 8; k++) { vals[k] = expf(vals[k] - m); sum += vals[k]; }
#pragma unroll
        for (int off = 32; off; off >>= 1) sum += __shfl_xor(sum, off);
        float* arow = attn + ((long)bh * 512 + (i0 + r)) * 512;
#pragma unroll
        for (int k = 0; k < 8; k++) {
            const float o = vals[k] / sum;
            arow[lane + 64 * k] = o;
            sc16[r][lane + 64 * k] = (_Float16)o;
        }
    }

    if (blockIdx.x == 0 && tid < 64) {
        int s = 0;
        for (int k = tid; k < 2048; k += 64) s += Ti[k];
#pragma unroll
        for (int off = 32; off; off >>= 1) s += __shfl_xor(s, off);
        if (tid == 0) regp[0] = 1e-3f * ((float)s / 2048.0f);
    }
    __syncthreads();

    // ---- fused AV: wave wid handles d-tile [wid*16, wid*16+16); B from vbits ----
    const int fr = lane & 15, fk = lane >> 4;
    f32x4 acc = {};
    const unsigned* vb = vbits + (long)b * 512 * 512 + h * 64 + wid * 16 + fr;
#pragma unroll
    for (int k0 = 0; k0 < 512; k0 += 32) {
        f16x8 av = *(const f16x8*)&sc16[fr][k0 + fk * 8];
        f16x8 bv;
#pragma unroll
        for (int e = 0; e < 8; e++) {
            const int s = k0 + fk * 8 + e;
            const unsigned vw = vb[(long)s * 512];
            bv[e] = (_Float16)((float)__popc(vw & tmask[s]) / 20.0f);
        }
        acc = __builtin_amdgcn_mfma_f32_16x16x32_f16(av, bv, acc, 0, 0, 0);
    }
    const int d = wid * 16 + fr;
#pragma unroll
    for (int rr = 0; rr < 4; rr++) {
        const int i = i0 + fk * 4 + rr;
        hout[(b * 512 + i) * 512 + h * 64 + d] = (_Float16)acc[rr];
    }
}

// ---------------- Kernel 4: Wo projection, fused fp32->fp16 weight convert ----------------
// BM=32, BN=64 -> grid (8,64) = 512 blocks (2/CU).
__global__ __launch_bounds__(256) void k_gemmWo(
    const _Float16* __restrict__ A, const float* __restrict__ Wo,
    const float* __restrict__ bias, float* __restrict__ Y)
{
    __shared__ _Float16 As[4][32][8];
    __shared__ _Float16 Bs[4][64][8];

    const int bn = blockIdx.x * 64, bm = blockIdx.y * 32;
    const int tid = threadIdx.x, w = tid >> 6, l = tid & 63;
    const int nB = w * 16;                    // wave-tile 32(m) x 16(n)
    const int sr = tid >> 2, sk = tid & 3;    // B staging
    const int ar = tid >> 3, ak = tid & 3;    // A staging (half the threads)
    const int fr = l & 15, fk = l >> 4;

    f32x4 acc[2] = {};

    const float* bsrc = Wo + (bn + sr) * 512;
    const bool doA = ((tid & 4) == 0);
    uint4 pA = {};
    if (doA) pA = *(const uint4*)(A + (bm + ar) * 512 + ak * 8);
    float4 pb0 = *(const float4*)(bsrc + sk * 8);
    float4 pb1 = *(const float4*)(bsrc + sk * 8 + 4);

    for (int k0 = 0; k0 < 512; k0 += 32) {
        __syncthreads();
        {
            HU4 h0, h1;
            cast4(pb0, h0); cast4(pb1, h1);
            if (doA) *(uint4*)&As[ak][ar][0] = pA;
            *(ushort4*)&Bs[sk][sr][0] = h0.u; *(ushort4*)&Bs[sk][sr][4] = h1.u;
        }
        __syncthreads();
        const int kn = (k0 + 32) & 511;
        if (doA) pA = *(const uint4*)(A + (bm + ar) * 512 + kn + ak * 8);
        pb0 = *(const float4*)(bsrc + kn + sk * 8);
        pb1 = *(const float4*)(bsrc + kn + sk * 8 + 4);

        f16x8 bh = *(const f16x8*)&Bs[fk][nB + fr][0];
#pragma unroll
        for (int mt = 0; mt < 2; mt++) {
            f16x8 ah = *(const f16x8*)&As[fk][mt * 16 + fr][0];
            acc[mt] = __builtin_amdgcn_mfma_f32_16x16x32_f16(ah, bh, acc[mt], 0, 0, 0);
        }
    }

#pragma unroll
    for (int mt = 0; mt < 2; mt++) {
        const int j = bn + nB + fr;
        const float badd = bias[j];
#pragma unroll
        for (int rr = 0; rr < 4; rr++) {
            const int i = bm + mt * 16 + fk * 4 + rr;
            Y[i * 512 + j] = acc[mt][rr] + badd;
        }
    }
}

extern "C" void kernel_launch(void* const* d_in, const int* in_sizes, int n_in,
                              void* d_out, int out_size, void* d_ws, size_t ws_size,
                              hipStream_t stream)
{
    const float* x    = (const float*)d_in[0];
    const float* Wq   = (const float*)d_in[1];
    const float* Wk   = (const float*)d_in[2];
    const float* Wv   = (const float*)d_in[3];
    const float* Wo   = (const float*)d_in[4];
    const float* bo   = (const float*)d_in[5];
    const float* gw1  = (const float*)d_in[6];
    const float* gb1  = (const float*)d_in[7];
    const float* gw2  = (const float*)d_in[8];
    const float* gb2  = (const float*)d_in[9];
    const float* gw3  = (const float*)d_in[10];
    const float* gb3  = (const float*)d_in[11];
    const float* cw1  = (const float*)d_in[12];
    const float* cb1  = (const float*)d_in[13];
    const float* cw2  = (const float*)d_in[14];
    const float* cb2  = (const float*)d_in[15];
    const float* alpha = (const float*)d_in[16];
    const float* beta  = (const float*)d_in[17];

    float* out   = (float*)d_out;                 // [2048*512]
    float* attn  = out + 1048576;                 // [32][512][512]
    float* regp  = out + 1048576 + 8388608;
    float* tiout = regp + 1;

    // workspace (~12.6 MB):
    char* ws = (char*)d_ws;
    unsigned long long* qb = (unsigned long long*)ws;                // 2.62 MB
    unsigned long long* kb = (unsigned long long*)(ws + 2621440);    // 2.62 MB
    unsigned* vbits  = (unsigned*)(ws + 5242880);                    // [2048][512] 4 MB
    float*    h1buf  = (float*)(ws + 9437184);                       // [2048][128] 1 MB
    _Float16* hout_h = (_Float16*)(ws + 10485760);                   // 2 MB
    int*      Ti     = (int*)(ws + 12582912);                        // 8 KB

    k_gemm3<<<dim3(26, 32), 256, 0, stream>>>(x, Wq, Wk, Wv, gw1, cw1,
                                              alpha, beta, qb, kb, vbits, h1buf);
    k_gates2<<<64, 256, 0, stream>>>(h1buf, gb1, cb1, gw2, gb2, gw3, gb3,
                                     cw2, cb2, Ti, tiout);
    k_scores_av<<<1024, 256, 0, stream>>>(qb, kb, vbits, attn, Ti, regp, hout_h);
    k_gemmWo<<<dim3(8, 64), 256, 0, stream>>>(hout_h, Wo, bo, out);
}

// Round 15
// 94.215 us; speedup vs baseline: 1.2691x; 1.2691x over previous
//
#include <hip/hip_runtime.h>
#include <cstdint>

// B=4, S=512, D=512, H=8, TM=20, DH=64
// out layout: out[1048576] | attn[8388608] | reg[1] | T_i[2048]  (all float)

typedef __attribute__((ext_vector_type(8))) _Float16 f16x8;
typedef __attribute__((ext_vector_type(4))) float f32x4;

__device__ __forceinline__ float sep_mad(float a, float b, float c) {
    // separate mul+add rounding (matches numpy), blocks FMA contraction:
    // spike threshold is discontinuous.
    float t = a * b;
    asm volatile("" : "+v"(t));
    return t + c;
}

union HU4 { _Float16 h[4]; ushort4 u; };
union HU8 { _Float16 h[8]; uint4 u; };
union HU2 { _Float16 h[2]; unsigned u; };

__device__ __forceinline__ void split4(float4 v, HU4& hi, HU4& lo) {
    hi.h[0] = (_Float16)v.x; lo.h[0] = (_Float16)(v.x - (float)hi.h[0]);
    hi.h[1] = (_Float16)v.y; lo.h[1] = (_Float16)(v.y - (float)hi.h[1]);
    hi.h[2] = (_Float16)v.z; lo.h[2] = (_Float16)(v.z - (float)hi.h[2]);
    hi.h[3] = (_Float16)v.w; lo.h[3] = (_Float16)(v.w - (float)hi.h[3]);
}

__device__ __forceinline__ void cast4(float4 v, HU4& hi) {
    hi.h[0] = (_Float16)v.x; hi.h[1] = (_Float16)v.y;
    hi.h[2] = (_Float16)v.z; hi.h[3] = (_Float16)v.w;
}

// ---------------- Kernel 1: mixed-precision MFMA GEMM, fused fp32->fp16 split ----------------
// Y[2048][1664] = x @ [Wq|Wk|Wv|gw1|cw1|pad]^T.
// QKV N-blocks (bn<1536): plain fp16 (proven r5/r6, absmax 0.146).
// Gate N-blocks (bn>=1536): fp16x3 hi/lo -- T_i must be exact.
__global__ __launch_bounds__(256) void k_gemm3(
    const float* __restrict__ X,
    const float* __restrict__ Wq, const float* __restrict__ Wk,
    const float* __restrict__ Wv, const float* __restrict__ gw1,
    const float* __restrict__ cw1,
    float* __restrict__ Y)
{
    __shared__ _Float16 AsH[4][64][8];
    __shared__ _Float16 BsH[4][64][8];
    __shared__ _Float16 AsL[4][64][8];
    __shared__ _Float16 BsL[4][64][8];

    const int bn = blockIdx.x * 64, bm = blockIdx.y * 64;
    const int tid = threadIdx.x, w = tid >> 6, l = tid & 63;
    const int mB = (w & 1) * 32, nB = (w >> 1) * 32;
    const int sr = tid >> 2, sk = tid & 3;
    const int fr = l & 15, fk = l >> 4;
    const bool gate = (bn >= 1536);           // block-uniform

    const float* asrc = X + (bm + sr) * 512;
    const int brow = bn + sr;
    const float* bsrc;
    bool bvalid = true;
    if      (brow < 512)  bsrc = Wq  + brow * 512;
    else if (brow < 1024) bsrc = Wk  + (brow - 512) * 512;
    else if (brow < 1536) bsrc = Wv  + (brow - 1024) * 512;
    else if (brow < 1600) bsrc = gw1 + (brow - 1536) * 512;
    else if (brow < 1632) bsrc = cw1 + (brow - 1600) * 512;
    else { bsrc = Wq; bvalid = false; }

    f32x4 acc[2][2] = {};
    const float4 z4{0.f, 0.f, 0.f, 0.f};

    float4 pa0 = *(const float4*)(asrc + sk * 8);
    float4 pa1 = *(const float4*)(asrc + sk * 8 + 4);
    float4 pb0 = bvalid ? *(const float4*)(bsrc + sk * 8)     : z4;
    float4 pb1 = bvalid ? *(const float4*)(bsrc + sk * 8 + 4) : z4;

    for (int k0 = 0; k0 < 512; k0 += 32) {
        __syncthreads();
        if (gate) {
            HU4 h0, l0, h1, l1;
            split4(pa0, h0, l0); split4(pa1, h1, l1);
            *(ushort4*)&AsH[sk][sr][0] = h0.u; *(ushort4*)&AsH[sk][sr][4] = h1.u;
            *(ushort4*)&AsL[sk][sr][0] = l0.u; *(ushort4*)&AsL[sk][sr][4] = l1.u;
            split4(pb0, h0, l0); split4(pb1, h1, l1);
            *(ushort4*)&BsH[sk][sr][0] = h0.u; *(ushort4*)&BsH[sk][sr][4] = h1.u;
            *(ushort4*)&BsL[sk][sr][0] = l0.u; *(ushort4*)&BsL[sk][sr][4] = l1.u;
        } else {
            HU4 h0, h1;
            cast4(pa0, h0); cast4(pa1, h1);
            *(ushort4*)&AsH[sk][sr][0] = h0.u; *(ushort4*)&AsH[sk][sr][4] = h1.u;
            cast4(pb0, h0); cast4(pb1, h1);
            *(ushort4*)&BsH[sk][sr][0] = h0.u; *(ushort4*)&BsH[sk][sr][4] = h1.u;
        }
        __syncthreads();
        const int kn = (k0 + 32) & 511;   // wraps harmlessly on last iter
        pa0 = *(const float4*)(asrc + kn + sk * 8);
        pa1 = *(const float4*)(asrc + kn + sk * 8 + 4);
        if (bvalid) {
            pb0 = *(const float4*)(bsrc + kn + sk * 8);
            pb1 = *(const float4*)(bsrc + kn + sk * 8 + 4);
        }

        f16x8 ah[2];
#pragma unroll
        for (int mt = 0; mt < 2; mt++)
            ah[mt] = *(const f16x8*)&AsH[fk][mB + mt * 16 + fr][0];
        if (gate) {
            f16x8 al[2];
#pragma unroll
            for (int mt = 0; mt < 2; mt++)
                al[mt] = *(const f16x8*)&AsL[fk][mB + mt * 16 + fr][0];
#pragma unroll
            for (int nt = 0; nt < 2; nt++) {
                f16x8 bh = *(const f16x8*)&BsH[fk][nB + nt * 16 + fr][0];
                f16x8 bl = *(const f16x8*)&BsL[fk][nB + nt * 16 + fr][0];
#pragma unroll
                for (int mt = 0; mt < 2; mt++) {
                    acc[mt][nt] = __builtin_amdgcn_mfma_f32_16x16x32_f16(ah[mt], bh, acc[mt][nt], 0, 0, 0);
                    acc[mt][nt] = __builtin_amdgcn_mfma_f32_16x16x32_f16(ah[mt], bl, acc[mt][nt], 0, 0, 0);
                    acc[mt][nt] = __builtin_amdgcn_mfma_f32_16x16x32_f16(al[mt], bh, acc[mt][nt], 0, 0, 0);
                }
            }
        } else {
#pragma unroll
            for (int nt = 0; nt < 2; nt++) {
                f16x8 bh = *(const f16x8*)&BsH[fk][nB + nt * 16 + fr][0];
#pragma unroll
                for (int mt = 0; mt < 2; mt++)
                    acc[mt][nt] = __builtin_amdgcn_mfma_f32_16x16x32_f16(ah[mt], bh, acc[mt][nt], 0, 0, 0);
            }
        }
    }

#pragma unroll
    for (int mt = 0; mt < 2; mt++) {
#pragma unroll
        for (int nt = 0; nt < 2; nt++) {
            const int j = bn + nB + nt * 16 + fr;
#pragma unroll
            for (int rr = 0; rr < 4; rr++) {
                const int i = bm + mB + mt * 16 + fk * 4 + rr;
                Y[i * 1664 + j] = acc[mt][nt][rr];
            }
        }
    }
}

// ---------------- Kernel 2: LIF + fused gate-layers-2/3 + ballot bit-pack + v_mean transpose ----
// grid (64, 32): blockIdx.y = bh, blockIdx.x = 8-token s-block. 256 thr = 4 waves,
// 2 LIF rounds -> 2048 blocks = 8 blocks/CU (max waves/SIMD) to hide the serial
// dependent sep_mad chain. Gate layers 2/3 recomputed per block (bit-identical).
__global__ __launch_bounds__(256) void k_lif(
    const float* __restrict__ qkvh1,         // [2048][1664]  (q|k|v|h1raw per row)
    const float* __restrict__ gb1, const float* __restrict__ cb1,
    const float* __restrict__ gw2, const float* __restrict__ gb2,
    const float* __restrict__ gw3, const float* __restrict__ gb3,
    const float* __restrict__ cw2, const float* __restrict__ cb2,
    const float* __restrict__ pAlpha, const float* __restrict__ pBeta,
    unsigned long long* __restrict__ qbits,  // [(bh*20)+t]*512 + s
    unsigned long long* __restrict__ kbits,
    _Float16* __restrict__ vmT,              // [bh][d][s]
    int* __restrict__ Ti, float* __restrict__ ti_out)
{
    __shared__ _Float16 cnts[64][10];        // [d][s_local 0..7], pad 10
    __shared__ float h1s[8][100];
    __shared__ float w2s[32][65];            // pad 65: conflict-free
    __shared__ float h2s[8][36];
    __shared__ int tis[8];
    const int tid = threadIdx.x;
    const int wid = tid >> 6, lane = tid & 63;
    const int bh = blockIdx.y, s0 = blockIdx.x * 8;
    const int b = bh >> 3, h = bh & 7;
    const float alpha = pAlpha[0], beta = pBeta[0];

    for (int i = tid; i < 2048; i += 256) w2s[i >> 6][i & 63] = gw2[i];
    for (int i = tid; i < 768; i += 256) {
        const int r = i / 96, c = i % 96;
        const float v = qkvh1[(long)(b * 512 + s0 + r) * 1664 + 1536 + c]
                        + (c < 64 ? gb1[c] : cb1[c - 64]);
        h1s[r][c] = fmaxf(v, 0.f);
    }
    __syncthreads();
    {
        const int tok = tid >> 5, o2 = tid & 31;   // 8 tokens x 32 outs = 256
        float a = gb2[o2];
        for (int k = 0; k < 64; k++) a = fmaf(w2s[o2][k], h1s[tok][k], a);
        h2s[tok][o2] = fmaxf(a, 0.f);
    }
    __syncthreads();
    if (tid < 8) {
        const int tok = tid;
        float gg = gb3[0], cc = cb2[0];
        for (int k = 0; k < 32; k++) {
            gg = fmaf(gw3[k], h2s[tok][k], gg);
            cc = fmaf(cw2[k], h1s[tok][64 + k], cc);
        }
        float g = 1.f / (1.f + expf(-gg));
        float c = 1.f / (1.f + expf(-cc));
        float p1 = 0.7f * g, p2 = 0.3f * c;
        asm volatile("" : "+v"(p1), "+v"(p2));
        float comb = p1 + p2;
        float tf = ceilf(comb * 20.0f);
        tf = fminf(fmaxf(tf, 1.f), 20.f);
        tis[tok] = (int)tf;
        Ti[b * 512 + s0 + tok] = (int)tf;        // redundant x8 across h, identical
        ti_out[b * 512 + s0 + tok] = tf;
    }
    __syncthreads();

    const float* qrow0 = qkvh1 + (long)(b * 512 + s0 + wid) * 1664 + h * 64 + lane;
    float cq = qrow0[0], ck = qrow0[512], cv = qrow0[1024];

    for (int r = 0; r < 2; r++) {
        const int tl = r * 4 + wid;              // token_local 0..7
        const int s = s0 + tl;
        float nq = 0.f, nk = 0.f, nv = 0.f;
        if (r < 1) {
            const float* qr = qkvh1 + (long)(b * 512 + s + 4) * 1664 + h * 64 + lane;
            nq = qr[0]; nk = qr[512]; nv = qr[1024];
        }
        const int T = tis[tl];
        float iq = 0.f, vq = 0.f, ik = 0.f, vk = 0.f, iv = 0.f, vv = 0.f;
        int cnt = 0;
        const int base = (bh * 20) * 512 + s;
#pragma unroll
        for (int t = 0; t < 20; t++) {
            iq = sep_mad(alpha, iq, cq); vq = sep_mad(beta, vq, iq);
            bool sq = vq >= 1.0f; vq = sq ? 0.f : vq;
            ik = sep_mad(alpha, ik, ck); vk = sep_mad(beta, vk, ik);
            bool sk = vk >= 1.0f; vk = sk ? 0.f : vk;
            iv = sep_mad(alpha, iv, cv); vv = sep_mad(beta, vv, iv);
            bool sv = vv >= 1.0f; vv = sv ? 0.f : vv;
            bool act = t < T;
            unsigned long long mq = __ballot(sq && act);
            unsigned long long mk = __ballot(sk && act);
            if (lane == 0) {
                qbits[base + t * 512] = mq;
                kbits[base + t * 512] = mk;
            }
            cnt += (sv && act) ? 1 : 0;
        }
        cnts[lane][tl] = (_Float16)((float)cnt / 20.0f);
        cq = nq; ck = nk; cv = nv;
    }
    __syncthreads();
    // write vmT[bh][d][s0..s0+7]: thread (d = tid>>2, q = tid&3) -> 2 fp16 = 4B
    const int d = tid >> 2, q = tid & 3;
    HU2 o;
    o.h[0] = cnts[d][q * 2];
    o.h[1] = cnts[d][q * 2 + 1];
    *(unsigned*)(vmT + (bh * 64 + d) * 512 + s0 + q * 2) = o.u;
}

// ---------------- Kernel 3: popcount scores + softmax -> attn + fused AV -> hout ----------------
// Block = (bh, 16 q-rows). After softmax the 16x512 attn tile is in LDS (fp16, exact
// conversion identical to old k_av staging) -> each wave MFMAs a 16x16 d-tile of hout.
__global__ __launch_bounds__(256) void k_scores_av(
    const unsigned long long* __restrict__ qbits,
    const unsigned long long* __restrict__ kbits,
    float* __restrict__ attn,
    const int* __restrict__ Ti, float* __restrict__ regp,
    const _Float16* __restrict__ vmT,   // [bh][d][s]
    _Float16* __restrict__ hout)        // [tok][h*64+d] fp16
{
    const int bh = blockIdx.x >> 5;            // 0..31
    const int i0 = (blockIdx.x & 31) * 16;
    const int base = bh * 20 * 512;
    __shared__ unsigned long long qs[20][16];
    __shared__ _Float16 sc16[16][520];         // pad 520: rows 1040B, 16B-aligned
    const int tid = threadIdx.x;
    for (int idx = tid; idx < 320; idx += 256) {
        int t = idx >> 4, r = idx & 15;
        qs[t][r] = qbits[base + t * 512 + i0 + r];
    }
    int Tmax = 0;
    const int tb = (bh >> 3) * 512 + i0;
#pragma unroll
    for (int r = 0; r < 16; r++) Tmax = max(Tmax, Ti[tb + r]);
    __syncthreads();

    {
        const unsigned long long* kbp = kbits + base + 2 * tid;
        int acc0[16] = {}, acc1[16] = {};
        for (int tc = 0; tc < 4; tc++) {
            if (tc * 5 >= Tmax) break;
            unsigned long long kv0[5], kv1[5];
#pragma unroll
            for (int t = 0; t < 5; t++) {
                ulonglong2 kk = *(const ulonglong2*)(kbp + (tc * 5 + t) * 512);
                kv0[t] = kk.x; kv1[t] = kk.y;
            }
#pragma unroll
            for (int r = 0; r < 16; r++) {
#pragma unroll
                for (int t = 0; t < 5; t++) {
                    unsigned long long qv = qs[tc * 5 + t][r];
                    acc0[r] += __popcll(qv & kv0[t]);
                    acc1[r] += __popcll(qv & kv1[t]);
                }
            }
        }
#pragma unroll
        for (int r = 0; r < 16; r++) {
            HU2 p;                              // counts <= 1280: *0.125 exact in fp16
            p.h[0] = (_Float16)((float)acc0[r] * 0.125f);
            p.h[1] = (_Float16)((float)acc1[r] * 0.125f);
            *(unsigned*)&sc16[r][2 * tid] = p.u;
        }
    }
    __syncthreads();

    const int wid = tid >> 6, lane = tid & 63;
#pragma unroll
    for (int rr = 0; rr < 4; rr++) {
        const int r = wid * 4 + rr;
        float vals[8];
        float m = -1e30f;
#pragma unroll
        for (int k = 0; k < 8; k++) { vals[k] = (float)sc16[r][lane + 64 * k]; m = fmaxf(m, vals[k]); }
#pragma unroll
        for (int off = 32; off; off >>= 1) m = fmaxf(m, __shfl_xor(m, off));
        float sum = 0.f;
#pragma unroll
        for (int k = 0; k < 8; k++) { vals[k] = expf(vals[k] - m); sum += vals[k]; }
#pragma unroll
        for (int off = 32; off; off >>= 1) sum += __shfl_xor(sum, off);
        float* arow = attn + ((long)bh * 512 + (i0 + r)) * 512;
#pragma unroll
        for (int k = 0; k < 8; k++) {
            const float o = vals[k] / sum;
            arow[lane + 64 * k] = o;
            sc16[r][lane + 64 * k] = (_Float16)o;   // same conversion old k_av applied
        }
    }

    if (blockIdx.x == 0 && tid < 64) {
        int s = 0;
        for (int k = tid; k < 2048; k += 64) s += Ti[k];
#pragma unroll
        for (int off = 32; off; off >>= 1) s += __shfl_xor(s, off);
        if (tid == 0) regp[0] = 1e-3f * ((float)s / 2048.0f);
    }
    __syncthreads();

    // ---- fused AV: wave wid handles d-tile [wid*16, wid*16+16) ----
    const int fr = lane & 15, fk = lane >> 4;
    const int b = bh >> 3, h = bh & 7;
    f32x4 acc = {};
    const _Float16* bsrc = vmT + (bh * 64 + wid * 16 + fr) * 512;
#pragma unroll
    for (int k0 = 0; k0 < 512; k0 += 32) {
        f16x8 av = *(const f16x8*)&sc16[fr][k0 + fk * 8];
        f16x8 bv = *(const f16x8*)(bsrc + k0 + fk * 8);
        acc = __builtin_amdgcn_mfma_f32_16x16x32_f16(av, bv, acc, 0, 0, 0);
    }
    const int d = wid * 16 + fr;
#pragma unroll
    for (int rr = 0; rr < 4; rr++) {
        const int i = i0 + fk * 4 + rr;
        hout[(b * 512 + i) * 512 + h * 64 + d] = (_Float16)acc[rr];
    }
}

// ---------------- Kernel 4: Wo projection, fused fp32->fp16 weight convert ----------------
// BM=32, BN=64 -> grid (8,64) = 512 blocks (2/CU). Same K-order per output: bit-identical.
__global__ __launch_bounds__(256) void k_gemmWo(
    const _Float16* __restrict__ A, const float* __restrict__ Wo,
    const float* __restrict__ bias, float* __restrict__ Y)
{
    __shared__ _Float16 As[4][32][8];
    __shared__ _Float16 Bs[4][64][8];

    const int bn = blockIdx.x * 64, bm = blockIdx.y * 32;
    const int tid = threadIdx.x, w = tid >> 6, l = tid & 63;
    const int nB = w * 16;                    // wave-tile 32(m) x 16(n)
    const int sr = tid >> 2, sk = tid & 3;    // B staging: 64 rows x 4 kgroups
    const int ar = tid >> 3, ak = tid & 3;    // A staging: 128 threads, 32 rows x 4 kgroups
    const int fr = l & 15, fk = l >> 4;

    f32x4 acc[2] = {};

    const float* bsrc = Wo + (bn + sr) * 512;
    const bool doA = ((tid & 4) == 0);        // 128 threads stage A
    uint4 pA = {};
    if (doA) pA = *(const uint4*)(A + (bm + ar) * 512 + ak * 8);
    float4 pb0 = *(const float4*)(bsrc + sk * 8);
    float4 pb1 = *(const float4*)(bsrc + sk * 8 + 4);

    for (int k0 = 0; k0 < 512; k0 += 32) {
        __syncthreads();
        {
            HU4 h0, h1;
            cast4(pb0, h0); cast4(pb1, h1);
            if (doA) *(uint4*)&As[ak][ar][0] = pA;
            *(ushort4*)&Bs[sk][sr][0] = h0.u; *(ushort4*)&Bs[sk][sr][4] = h1.u;
        }
        __syncthreads();
        const int kn = (k0 + 32) & 511;
        if (doA) pA = *(const uint4*)(A + (bm + ar) * 512 + kn + ak * 8);
        pb0 = *(const float4*)(bsrc + kn + sk * 8);
        pb1 = *(const float4*)(bsrc + kn + sk * 8 + 4);

        f16x8 bh = *(const f16x8*)&Bs[fk][nB + fr][0];
#pragma unroll
        for (int mt = 0; mt < 2; mt++) {
            f16x8 ah = *(const f16x8*)&As[fk][mt * 16 + fr][0];
            acc[mt] = __builtin_amdgcn_mfma_f32_16x16x32_f16(ah, bh, acc[mt], 0, 0, 0);
        }
    }

#pragma unroll
    for (int mt = 0; mt < 2; mt++) {
        const int j = bn + nB + fr;
        const float badd = bias[j];
#pragma unroll
        for (int rr = 0; rr < 4; rr++) {
            const int i = bm + mt * 16 + fk * 4 + rr;
            Y[i * 512 + j] = acc[mt][rr] + badd;
        }
    }
}

extern "C" void kernel_launch(void* const* d_in, const int* in_sizes, int n_in,
                              void* d_out, int out_size, void* d_ws, size_t ws_size,
                              hipStream_t stream)
{
    const float* x    = (const float*)d_in[0];
    const float* Wq   = (const float*)d_in[1];
    const float* Wk   = (const float*)d_in[2];
    const float* Wv   = (const float*)d_in[3];
    const float* Wo   = (const float*)d_in[4];
    const float* bo   = (const float*)d_in[5];
    const float* gw1  = (const float*)d_in[6];
    const float* gb1  = (const float*)d_in[7];
    const float* gw2  = (const float*)d_in[8];
    const float* gb2  = (const float*)d_in[9];
    const float* gw3  = (const float*)d_in[10];
    const float* gb3  = (const float*)d_in[11];
    const float* cw1  = (const float*)d_in[12];
    const float* cb1  = (const float*)d_in[13];
    const float* cw2  = (const float*)d_in[14];
    const float* cb2  = (const float*)d_in[15];
    const float* alpha = (const float*)d_in[16];
    const float* beta  = (const float*)d_in[17];

    float* out   = (float*)d_out;                 // [2048*512]
    float* attn  = out + 1048576;                 // [32][512][512]
    float* regp  = out + 1048576 + 8388608;
    float* tiout = regp + 1;

    // workspace (~23.1 MB, no aliasing):
    char* ws = (char*)d_ws;
    float*    qkvh1  = (float*)ws;                            // [2048][1664] fp32, 13.63 MB
    unsigned long long* qb = (unsigned long long*)(ws + 13631488);   // 2.62 MB
    unsigned long long* kb = (unsigned long long*)(ws + 16252928);   // 2.62 MB
    _Float16* vmT    = (_Float16*)(ws + 18874368);            // 2 MB
    _Float16* hout_h = (_Float16*)(ws + 20971520);            // 2 MB
    int*      Ti     = (int*)(ws + 23068672);                 // 8 KB

    k_gemm3<<<dim3(26, 32), 256, 0, stream>>>(x, Wq, Wk, Wv, gw1, cw1, qkvh1);
    k_lif<<<dim3(64, 32), 256, 0, stream>>>(qkvh1, gb1, cb1, gw2, gb2, gw3, gb3,
                                            cw2, cb2, alpha, beta, qb, kb, vmT, Ti, tiout);
    k_scores_av<<<1024, 256, 0, stream>>>(qb, kb, attn, Ti, regp, vmT, hout_h);
    k_gemmWo<<<dim3(8, 64), 256, 0, stream>>>(hout_h, Wo, bo, out);
}